// Round 3
// baseline (110.708 us; speedup 1.0000x reference)
//
#include <hip/hip_runtime.h>
#include <cmath>

#define IMG_W 1024
#define SROWS 38              // staged source rows (32 outputs + 6 halo)
#define SCST  73              // LDS row stride in float4 (70 used + swizzle room)
#define NCHUNK 18             // float4 col-chunks staged per row (72 cols)
#define NITEMS (SROWS * NCHUNK)   // 684

// separable Gaussian: w(ky,kx) = gv[ky]*gh[kx], 1/(8*pi) folded into gv
struct GK { float gh[7]; float gv[7]; };

// bank-spread swizzle on float4 column index (bijective within 64-blocks)
__device__ __forceinline__ int swz(int c) { return c ^ ((c >> 3) & 7); }

__device__ __forceinline__ float warp_block_sum(float v, float* wsum, int tx, int ty) {
    #pragma unroll
    for (int off = 32; off > 0; off >>= 1)
        v += __shfl_down(v, off, 64);
    if (tx == 0) wsum[ty] = v;
    __syncthreads();
    return wsum[0] + wsum[1] + wsum[2] + wsum[3];
}

__global__ __launch_bounds__(256, 2)
void mind_tile(const float* __restrict__ img1, const float* __restrict__ img2,
               float* __restrict__ partials, GK gk)
{
    __shared__ float4 s1[SROWS * SCST];    // 44384 B -> 2 blocks/CU (grid-limited)

    const int tx  = (int)threadIdx.x;       // 0..63
    const int ty  = (int)threadIdx.y;       // 0..3 (wave id)
    const int tid = ty * 64 + tx;
    const int x0  = 7 + 64 * (int)blockIdx.x;   // first output col of tile
    const int y0  = 7 + 32 * (int)blockIdx.y;   // first output row of tile
    const int x4  = x0 - 3;                     // float4-aligned staged origin

    // ---- stage: pointwise fields -> LDS, float4 loads, swizzled writes ----
    #pragma unroll
    for (int ii = 0; ii < 3; ++ii) {
        const int it = tid + 256 * ii;
        if (it < NITEMS) {
            const int r   = it / NCHUNK;
            const int j   = it - r * NCHUNK;
            const int sr  = min(y0 - 3 + r, 1023);   // clamp feeds only masked outputs
            const int srp = sr ^ 512;                // only in-bounds y-shift source
            const int scc = min(x4 + 4 * j, 1020);   // 4-aligned, in-bounds
            const int scp = scc ^ 512;               // only in-bounds x-shift source
            const float4 a  = *(const float4*)&img2[sr  * IMG_W + scc];
            const float4 b  = *(const float4*)&img2[sr  * IMG_W + scp];
            const float4 c2 = *(const float4*)&img2[srp * IMG_W + scc];
            const float4 d  = *(const float4*)&img2[srp * IMG_W + scp];
            const float4 u  = *(const float4*)&img1[sr  * IMG_W + scc];
            const float4 ub = *(const float4*)&img1[sr  * IMG_W + scp];
            const float4 uc = *(const float4*)&img1[srp * IMG_W + scc];
            float4* __restrict__ dst = &s1[r * SCST];
            #define MIND_FIELD(E, K) { \
                const float a2 = a.E * a.E; \
                const float tb = a.E - b.E, tc = a.E - c2.E, td = a.E - d.E; \
                const float su = u.E - ub.E, sv = u.E - uc.E; \
                float4 f; \
                f.x = fmaf(tb, tb, -a2);                           /* H */ \
                f.y = fmaf(tc, tc, -a2);                           /* V */ \
                f.z = fmaf(td, td, -a2);                           /* D */ \
                f.w = fmaf(u.E, u.E + u.E, fmaf(su, su, sv * sv)); /* U */ \
                dst[swz(4 * j + K)] = f; }
            MIND_FIELD(x, 0)
            MIND_FIELD(y, 1)
            MIND_FIELD(z, 2)
            MIND_FIELD(w, 3)
            #undef MIND_FIELD
        }
    }
    __syncthreads();

    // straddle detection: boundary between 511 and 512
    const bool xs = (x0 - 3 <= 511) && (x0 + 66 >= 512);   // only bx==7
    const bool ys = (y0 - 3 <= 511) && (y0 + 34 >= 512);   // only by==15

    const int s_    = tx & 31;                 // column strip: owns cols 2s_, 2s_+1
    const int rg    = 2 * ty + (tx >> 5);      // row group 0..7: rows 4rg..4rg+3
    const int colg0 = x0 + 2 * s_;             // global col of cc=0
    int coff[8];
    #pragma unroll
    for (int k = 0; k < 8; ++k) coff[k] = swz(2 * s_ + k);

    float tsum = 0.f;

    if (!xs && !ys) {
        // ================= FAST path: block-uniform masks ======================
        float Px[2][4] = {{0}}, Py[2][4] = {{0}}, Pd[2][4] = {{0}}, V4[2][4] = {{0}};
        #pragma unroll
        for (int r = 0; r < 10; ++r) {
            const int rowbase = (4 * rg + r) * SCST;
            float4 f[8];
            #pragma unroll
            for (int k = 0; k < 8; ++k) f[k] = s1[rowbase + coff[k]];
            #pragma unroll
            for (int cc = 0; cc < 2; ++cc) {
                float hH = 0, hV = 0, hD = 0, hU = 0;
                #pragma unroll
                for (int k = 0; k < 7; ++k) {
                    const float4 g = f[k + cc];
                    hH = fmaf(gk.gh[k], g.x, hH);
                    hV = fmaf(gk.gh[k], g.y, hV);
                    hD = fmaf(gk.gh[k], g.z, hD);
                    hU = fmaf(gk.gh[k], g.w, hU);
                }
                #pragma unroll
                for (int o = 0; o < 4; ++o) {
                    if (r - o >= 0 && r - o <= 6) {          // compile-time pruned
                        const float g = gk.gv[r - o];
                        Px[cc][o] = fmaf(g, hH, Px[cc][o]);
                        Py[cc][o] = fmaf(g, hV, Py[cc][o]);
                        Pd[cc][o] = fmaf(g, hD, Pd[cc][o]);
                        V4[cc][o] = fmaf(g, hU, V4[cc][o]);
                    }
                }
            }
        }
        #pragma unroll
        for (int cc = 0; cc < 2; ++cc) {
            const bool xok = (colg0 + cc <= 1016);
            #pragma unroll
            for (int o = 0; o < 4; ++o) {
                const float V = fmaf(V4[cc][o], 0.25f, 1e-5f);
                const float invV = 1.0f / V;
                float M = fminf(0.f, Px[cc][o]);
                M = fminf(M, Py[cc][o]); M = fminf(M, Pd[cc][o]);
                // 5 of the 8 near-shift maps equal T0 here -> join the 72 far shifts
                const float pix = 77.f * __expf(M * invV)
                    + __expf((M - Px[cc][o]) * invV)
                    + __expf((M - Py[cc][o]) * invV)
                    + __expf((M - Pd[cc][o]) * invV);
                const bool ok = xok && (y0 + 4 * rg + o <= 1017);
                tsum += ok ? pix : 0.f;
            }
        }
    } else {
        // ================= GENERAL path: boundary-straddling blocks ============
        float glx[2][7], ghx[2][7];
        #pragma unroll
        for (int cc = 0; cc < 2; ++cc)
            #pragma unroll
            for (int k = 0; k < 7; ++k) {
                const bool lo = (((x4 + 2 * s_ + cc + k) & 512) == 0);
                glx[cc][k] = lo ? gk.gh[k] : 0.f;
                ghx[cc][k] = lo ? 0.f : gk.gh[k];
            }
        float Ph[2][4]  = {{0}}, Qh[2][4]  = {{0}}, Pv[2][4] = {{0}}, Qv[2][4] = {{0}};
        float Ppp[2][4] = {{0}}, Ppm[2][4] = {{0}}, Pmp[2][4] = {{0}}, Pmm[2][4] = {{0}};
        float V4[2][4]  = {{0}};
        #pragma unroll
        for (int r = 0; r < 10; ++r) {
            const int rowbase = (4 * rg + r) * SCST;
            float4 f[8];
            #pragma unroll
            for (int k = 0; k < 8; ++k) f[k] = s1[rowbase + coff[k]];
            const bool ylo = (((y0 + 4 * rg - 3 + r) & 512) == 0);
            #pragma unroll
            for (int cc = 0; cc < 2; ++cc) {
                float hHlo = 0, hHhi = 0, hV = 0, hDlo = 0, hDhi = 0, hU = 0;
                #pragma unroll
                for (int k = 0; k < 7; ++k) {
                    const float4 g = f[k + cc];
                    hHlo = fmaf(glx[cc][k], g.x, hHlo);
                    hHhi = fmaf(ghx[cc][k], g.x, hHhi);
                    hV   = fmaf(gk.gh[k],   g.y, hV);
                    hDlo = fmaf(glx[cc][k], g.z, hDlo);
                    hDhi = fmaf(ghx[cc][k], g.z, hDhi);
                    hU   = fmaf(gk.gh[k],   g.w, hU);
                }
                #pragma unroll
                for (int o = 0; o < 4; ++o) {
                    if (r - o >= 0 && r - o <= 6) {
                        const float g  = gk.gv[r - o];
                        const float wl = ylo ? g : 0.f;
                        const float wh = ylo ? 0.f : g;
                        Ph [cc][o] = fmaf(g,  hHlo, Ph [cc][o]);
                        Qh [cc][o] = fmaf(g,  hHhi, Qh [cc][o]);
                        Pv [cc][o] = fmaf(wl, hV,   Pv [cc][o]);
                        Qv [cc][o] = fmaf(wh, hV,   Qv [cc][o]);
                        Ppp[cc][o] = fmaf(wl, hDlo, Ppp[cc][o]);
                        Ppm[cc][o] = fmaf(wh, hDlo, Ppm[cc][o]);
                        Pmp[cc][o] = fmaf(wl, hDhi, Pmp[cc][o]);
                        Pmm[cc][o] = fmaf(wh, hDhi, Pmm[cc][o]);
                        V4 [cc][o] = fmaf(g,  hU,   V4 [cc][o]);
                    }
                }
            }
        }
        #pragma unroll
        for (int cc = 0; cc < 2; ++cc) {
            const bool xok = (colg0 + cc <= 1016);
            #pragma unroll
            for (int o = 0; o < 4; ++o) {
                const float V = fmaf(V4[cc][o], 0.25f, 1e-5f);
                const float invV = 1.0f / V;
                float M = fminf(0.f, Ph[cc][o]);
                M = fminf(M, Qh[cc][o]);  M = fminf(M, Pv[cc][o]);  M = fminf(M, Qv[cc][o]);
                M = fminf(M, Ppp[cc][o]); M = fminf(M, Pmp[cc][o]);
                M = fminf(M, Ppm[cc][o]); M = fminf(M, Pmm[cc][o]);
                const float pix = 72.f * __expf(M * invV)
                    + __expf((M - Ph [cc][o]) * invV) + __expf((M - Qh [cc][o]) * invV)
                    + __expf((M - Pv [cc][o]) * invV) + __expf((M - Qv [cc][o]) * invV)
                    + __expf((M - Ppp[cc][o]) * invV) + __expf((M - Pmp[cc][o]) * invV)
                    + __expf((M - Ppm[cc][o]) * invV) + __expf((M - Pmm[cc][o]) * invV);
                const bool ok = xok && (y0 + 4 * rg + o <= 1017);
                tsum += ok ? pix : 0.f;
            }
        }
    }

    // ---- per-block partial to workspace (NO fence, NO same-address atomics) ----
    __shared__ float wsum[4];
    const float bt = warp_block_sum(tsum, wsum, tx, ty);
    if (tid == 0)
        partials[(int)blockIdx.y * gridDim.x + (int)blockIdx.x] = bt;
}

__global__ __launch_bounds__(256)
void mind_reduce(const float* __restrict__ partials, float* __restrict__ out)
{
    // 512 partials, one block
    float s = partials[(int)threadIdx.x] + partials[(int)threadIdx.x + 256];
    double d = (double)s;
    #pragma unroll
    for (int off = 32; off > 0; off >>= 1)
        d += __shfl_down(d, off, 64);
    __shared__ double sm[4];
    const int lane = (int)threadIdx.x & 63, wid = (int)threadIdx.x >> 6;
    if (lane == 0) sm[wid] = d;
    __syncthreads();
    if (threadIdx.x == 0)
        out[0] = (float)((sm[0] + sm[1] + sm[2] + sm[3]) / 81688800.0);  // 80*1011*1010
}

extern "C" void kernel_launch(void* const* d_in, const int* in_sizes, int n_in,
                              void* d_out, int out_size, void* d_ws, size_t ws_size,
                              hipStream_t stream) {
    const float* img1 = (const float*)d_in[0];
    const float* img2 = (const float*)d_in[1];
    float* out = (float*)d_out;
    float* partials = (float*)d_ws;

    GK gk;
    for (int i = 0; i < 7; ++i) {
        const double dv = i - 3;
        gk.gh[i] = (float)std::exp(-(dv * dv) / 8.0);
        gk.gv[i] = (float)(std::exp(-(dv * dv) / 8.0) / (8.0 * M_PI));
    }

    dim3 block(64, 4);
    dim3 grid(16, 32);   // 512 blocks, 64x32 tiles
    mind_tile<<<grid, block, 0, stream>>>(img1, img2, partials, gk);
    mind_reduce<<<1, 256, 0, stream>>>(partials, out);
}

// Round 4
// 70.422 us; speedup vs baseline: 1.5721x; 1.5721x over previous
//
#include <hip/hip_runtime.h>
#include <cmath>

#define IMG_W 1024
#define SROWS 22              // staged source rows (16 outputs + 6 halo)
#define SCST  73              // LDS row stride in float4 (72 used, odd stride)
#define NCHUNK 18             // float4 col-chunks staged per row (72 cols)
#define NITEMS (SROWS * NCHUNK)   // 396

// separable Gaussian: w(ky,kx) = gv[ky]*gh[kx], 1/(8*pi) folded into gv
struct GK { float gh[7]; float gv[7]; };

// bank-spread swizzle on float4 column index (bijective within each 8-block)
__device__ __forceinline__ int swz(int c) { return c ^ ((c >> 3) & 7); }

__device__ __forceinline__ float warp_block_sum(float v, float* wsum, int tx, int ty) {
    #pragma unroll
    for (int off = 32; off > 0; off >>= 1)
        v += __shfl_down(v, off, 64);
    if (tx == 0) wsum[ty] = v;
    __syncthreads();
    return wsum[0] + wsum[1] + wsum[2] + wsum[3];
}

__global__ __launch_bounds__(256)
void mind_tile(const float* __restrict__ img1, const float* __restrict__ img2,
               float* __restrict__ partials, GK gk)
{
    __shared__ float4 s1[SROWS * SCST];    // 25696 B -> 4 blocks/CU (grid-limited)

    const int tx  = (int)threadIdx.x;       // 0..63 : output col owner
    const int ty  = (int)threadIdx.y;       // 0..3  : 4-row group owner (== wave id)
    const int tid = ty * 64 + tx;
    // straddle-first launch-order remap (bijective relabel; partials keep real ids)
    const int bx  = ((int)blockIdx.x + 7)  & 15;
    const int by  = ((int)blockIdx.y + 31) & 63;
    const int x0  = 7 + 64 * bx;            // first output col of tile
    const int y0  = 7 + 16 * by;            // first output row of tile
    const int x4  = x0 - 3;                 // float4-aligned staged origin

    // ---- phase A: pointwise fields -> LDS (float4 loads, swizzled writes) ----
    #pragma unroll
    for (int ii = 0; ii < 2; ++ii) {
        const int it = tid + 256 * ii;
        if (it < NITEMS) {
            const int r   = it / NCHUNK;
            const int j   = it - r * NCHUNK;
            const int sr  = min(y0 - 3 + r, 1023);   // clamp feeds only masked outputs
            const int srp = sr ^ 512;                // only in-bounds y-shift source
            const int scc = min(x4 + 4 * j, 1020);   // 4-aligned, in-bounds
            const int scp = scc ^ 512;               // only in-bounds x-shift source
            const float4 a  = *(const float4*)&img2[sr  * IMG_W + scc];
            const float4 b  = *(const float4*)&img2[sr  * IMG_W + scp];
            const float4 c2 = *(const float4*)&img2[srp * IMG_W + scc];
            const float4 d  = *(const float4*)&img2[srp * IMG_W + scp];
            const float4 u  = *(const float4*)&img1[sr  * IMG_W + scc];
            const float4 ub = *(const float4*)&img1[sr  * IMG_W + scp];
            const float4 uc = *(const float4*)&img1[srp * IMG_W + scc];
            float4* __restrict__ dst = &s1[r * SCST];
            #define MIND_FIELD(E, K) { \
                const float a2 = a.E * a.E; \
                const float tb = a.E - b.E, tc = a.E - c2.E, td = a.E - d.E; \
                const float su = u.E - ub.E, sv = u.E - uc.E; \
                float4 f; \
                f.x = fmaf(tb, tb, -a2);                           /* H */ \
                f.y = fmaf(tc, tc, -a2);                           /* V */ \
                f.z = fmaf(td, td, -a2);                           /* D */ \
                f.w = fmaf(u.E, u.E + u.E, fmaf(su, su, sv * sv)); /* U */ \
                dst[swz(4 * j + K)] = f; }
            MIND_FIELD(x, 0)
            MIND_FIELD(y, 1)
            MIND_FIELD(z, 2)
            MIND_FIELD(w, 3)
            #undef MIND_FIELD
        }
    }
    __syncthreads();

    // straddle detection: boundary lies between 511 and 512
    const bool xs = (x0 - 3 <= 511) && (x0 + 66 >= 512);   // only bx==7
    const bool ys = (y0 - 3 <= 511) && (y0 + 18 >= 512);   // only by==31
    const bool straddle = xs || ys;            // block-uniform

    // ---- phase B: horizontal conv raw -> h, IN PLACE (non-straddle only) ----
    // 176 tasks: (row 0..21) x (8-col segment 0..7). All reads land in regs
    // before the barrier; writes go to slots swz(0..63) of the same row after.
    float4 hv[8];
    const int brow = tid >> 3, bseg = tid & 7;
    const bool btask = (!straddle) && (tid < 176);
    if (btask) {
        const float4* __restrict__ rb = &s1[brow * SCST];
        float4 f[14];
        #pragma unroll
        for (int q = 0; q < 14; ++q) f[q] = rb[swz(8 * bseg + q)];
        #pragma unroll
        for (int o = 0; o < 8; ++o) {
            float hH = 0, hV = 0, hD = 0, hU = 0;
            #pragma unroll
            for (int k = 0; k < 7; ++k) {
                const float4 g = f[o + k];
                hH = fmaf(gk.gh[k], g.x, hH);
                hV = fmaf(gk.gh[k], g.y, hV);
                hD = fmaf(gk.gh[k], g.z, hD);
                hU = fmaf(gk.gh[k], g.w, hU);
            }
            hv[o] = make_float4(hH, hV, hD, hU);
        }
    }
    __syncthreads();
    if (btask) {
        float4* __restrict__ rb = &s1[brow * SCST];
        #pragma unroll
        for (int o = 0; o < 8; ++o) rb[swz(8 * bseg + o)] = hv[o];
    }
    __syncthreads();

    const bool xok = (x0 + tx <= 1016);
    float tsum = 0.f;

    if (!straddle) {
        // ============ FAST path: vertical conv over precomputed h ============
        const int ci = swz(tx);
        float Px[4] = {0,0,0,0}, Py[4] = {0,0,0,0}, Pd[4] = {0,0,0,0}, V4[4] = {0,0,0,0};
        #pragma unroll
        for (int r = 0; r < 10; ++r) {
            const float4 h = s1[(4 * ty + r) * SCST + ci];
            #pragma unroll
            for (int o = 0; o < 4; ++o) {
                if (r - o >= 0 && r - o <= 6) {          // compile-time pruned
                    const float g = gk.gv[r - o];
                    Px[o] = fmaf(g, h.x, Px[o]);
                    Py[o] = fmaf(g, h.y, Py[o]);
                    Pd[o] = fmaf(g, h.z, Pd[o]);
                    V4[o] = fmaf(g, h.w, V4[o]);
                }
            }
        }
        #pragma unroll
        for (int o = 0; o < 4; ++o) {
            const float V = fmaf(V4[o], 0.25f, 1e-5f);
            const float invV = 1.0f / V;
            float M = fminf(0.f, Px[o]);
            M = fminf(M, Py[o]); M = fminf(M, Pd[o]);
            // 5 of the 8 near-shift maps equal T0 here -> join the 72 far shifts
            const float pix = 77.f * __expf(M * invV)
                + __expf((M - Px[o]) * invV)
                + __expf((M - Py[o]) * invV)
                + __expf((M - Pd[o]) * invV);
            const bool ok = xok && (y0 + 4 * ty + o <= 1017);
            tsum += ok ? pix : 0.f;
        }
    } else {
        // ============ GENERAL path: raw intact (phase B skipped) =============
        float glx[7], ghx[7];
        int cidx[7];
        #pragma unroll
        for (int kx = 0; kx < 7; ++kx) {
            const bool lo = (((x0 - 3 + tx + kx) & 512) == 0);
            glx[kx] = lo ? gk.gh[kx] : 0.f;
            ghx[kx] = lo ? 0.f : gk.gh[kx];
            cidx[kx] = swz(tx + kx);
        }
        float Ph[4]  = {0,0,0,0}, Qh[4]  = {0,0,0,0}, Pv[4] = {0,0,0,0}, Qv[4] = {0,0,0,0};
        float Ppp[4] = {0,0,0,0}, Ppm[4] = {0,0,0,0}, Pmp[4] = {0,0,0,0}, Pmm[4] = {0,0,0,0};
        float V4[4]  = {0,0,0,0};
        #pragma unroll
        for (int r = 0; r < 10; ++r) {
            const float4* __restrict__ row = &s1[(4 * ty + r) * SCST];
            float hHlo = 0, hHhi = 0, hV = 0, hDlo = 0, hDhi = 0, hU = 0;
            #pragma unroll
            for (int kx = 0; kx < 7; ++kx) {
                const float4 g = row[cidx[kx]];
                hHlo = fmaf(glx[kx],   g.x, hHlo);
                hHhi = fmaf(ghx[kx],   g.x, hHhi);
                hV   = fmaf(gk.gh[kx], g.y, hV);
                hDlo = fmaf(glx[kx],   g.z, hDlo);
                hDhi = fmaf(ghx[kx],   g.z, hDhi);
                hU   = fmaf(gk.gh[kx], g.w, hU);
            }
            const bool ylo = (((y0 + 4 * ty - 3 + r) & 512) == 0);
            #pragma unroll
            for (int o = 0; o < 4; ++o) {
                if (r - o >= 0 && r - o <= 6) {
                    const float g  = gk.gv[r - o];
                    const float wl = ylo ? g : 0.f;
                    const float wh = ylo ? 0.f : g;
                    Ph [o] = fmaf(g,  hHlo, Ph [o]);
                    Qh [o] = fmaf(g,  hHhi, Qh [o]);
                    Pv [o] = fmaf(wl, hV,   Pv [o]);
                    Qv [o] = fmaf(wh, hV,   Qv [o]);
                    Ppp[o] = fmaf(wl, hDlo, Ppp[o]);
                    Ppm[o] = fmaf(wh, hDlo, Ppm[o]);
                    Pmp[o] = fmaf(wl, hDhi, Pmp[o]);
                    Pmm[o] = fmaf(wh, hDhi, Pmm[o]);
                    V4 [o] = fmaf(g,  hU,   V4 [o]);
                }
            }
        }
        #pragma unroll
        for (int o = 0; o < 4; ++o) {
            const float V = fmaf(V4[o], 0.25f, 1e-5f);
            const float invV = 1.0f / V;
            float M = fminf(0.f, Ph[o]);
            M = fminf(M, Qh[o]);  M = fminf(M, Pv[o]);  M = fminf(M, Qv[o]);
            M = fminf(M, Ppp[o]); M = fminf(M, Pmp[o]); M = fminf(M, Ppm[o]); M = fminf(M, Pmm[o]);
            const float pix = 72.f * __expf(M * invV)
                + __expf((M - Ph [o]) * invV) + __expf((M - Qh [o]) * invV)
                + __expf((M - Pv [o]) * invV) + __expf((M - Qv [o]) * invV)
                + __expf((M - Ppp[o]) * invV) + __expf((M - Pmp[o]) * invV)
                + __expf((M - Ppm[o]) * invV) + __expf((M - Pmm[o]) * invV);
            const bool ok = xok && (y0 + 4 * ty + o <= 1017);
            tsum += ok ? pix : 0.f;
        }
    }

    // ---- per-block partial to workspace (NO fence, NO same-address atomics) ----
    __shared__ float wsum[4];
    const float bt = warp_block_sum(tsum, wsum, tx, ty);
    if (tid == 0)
        partials[by * 16 + bx] = bt;
}

__global__ __launch_bounds__(256)
void mind_reduce(const float* __restrict__ partials, float* __restrict__ out)
{
    // 1024 partials, one block
    float s = 0.f;
    #pragma unroll
    for (int k = 0; k < 4; ++k)
        s += partials[(int)threadIdx.x + 256 * k];
    double d = (double)s;
    #pragma unroll
    for (int off = 32; off > 0; off >>= 1)
        d += __shfl_down(d, off, 64);
    __shared__ double sm[4];
    const int lane = (int)threadIdx.x & 63, wid = (int)threadIdx.x >> 6;
    if (lane == 0) sm[wid] = d;
    __syncthreads();
    if (threadIdx.x == 0)
        out[0] = (float)((sm[0] + sm[1] + sm[2] + sm[3]) / 81688800.0);  // 80*1011*1010
}

extern "C" void kernel_launch(void* const* d_in, const int* in_sizes, int n_in,
                              void* d_out, int out_size, void* d_ws, size_t ws_size,
                              hipStream_t stream) {
    const float* img1 = (const float*)d_in[0];
    const float* img2 = (const float*)d_in[1];
    float* out = (float*)d_out;
    float* partials = (float*)d_ws;

    GK gk;
    for (int i = 0; i < 7; ++i) {
        const double dv = i - 3;
        gk.gh[i] = (float)std::exp(-(dv * dv) / 8.0);
        gk.gv[i] = (float)(std::exp(-(dv * dv) / 8.0) / (8.0 * M_PI));
    }

    dim3 block(64, 4);
    dim3 grid(16, 64);   // 1024 blocks, 64x16 tiles
    mind_tile<<<grid, block, 0, stream>>>(img1, img2, partials, gk);
    mind_reduce<<<1, 256, 0, stream>>>(partials, out);
}